// Round 1
// baseline (756.856 us; speedup 1.0000x reference)
//
#include <hip/hip_runtime.h>

// ---------------------------------------------------------------------------
// GCN 3-layer forward: N=100k nodes, E=1.6M edges, F=H=128, G=128 graphs, C=2
// Strategy: build CSR (by target) once per call; per layer: aggregate-first
// (A_norm h) then dense GEMM with fused bias+ReLU (math-equivalent to ref).
// All fp32.
// ---------------------------------------------------------------------------

__global__ void k_init(int* __restrict__ cnt, float* __restrict__ pooled,
                       float* __restrict__ gcnt, int N) {
    int i = blockIdx.x * blockDim.x + threadIdx.x;
    if (i < N) cnt[i] = 0;
    if (i < 128 * 128) pooled[i] = 0.f;
    if (i < 128) gcnt[i] = 0.f;
}

__global__ void k_count(const int* __restrict__ col, int* __restrict__ cnt, int E) {
    int e = blockIdx.x * blockDim.x + threadIdx.x;
    if (e < E) atomicAdd(&cnt[col[e]], 1);
}

__global__ void k_dinv(const int* __restrict__ cnt, float* __restrict__ dinv, int N) {
    int i = blockIdx.x * blockDim.x + threadIdx.x;
    if (i < N) dinv[i] = rsqrtf((float)cnt[i] + 1.0f);  // deg = in-deg + self loop
}

// ---- exclusive scan of cnt[0..N) -> rowptr, 2-level -----------------------
__global__ void k_scan1(const int* __restrict__ cnt, int* __restrict__ incl,
                        int* __restrict__ bsums, int N) {
    __shared__ int s[1024];
    int t = threadIdx.x;
    int idx = blockIdx.x * 1024 + t;
    int x = (idx < N) ? cnt[idx] : 0;
    s[t] = x;
    for (int off = 1; off < 1024; off <<= 1) {
        __syncthreads();
        int v = (t >= off) ? s[t - off] : 0;
        __syncthreads();
        s[t] += v;
    }
    __syncthreads();
    if (idx < N) incl[idx] = s[t];
    if (t == 1023) bsums[blockIdx.x] = s[1023];
}

__global__ void k_scan2(const int* __restrict__ bsums, int* __restrict__ boff, int nb) {
    __shared__ int s[1024];
    int t = threadIdx.x;
    int x = (t < nb) ? bsums[t] : 0;
    s[t] = x;
    for (int off = 1; off < 1024; off <<= 1) {
        __syncthreads();
        int v = (t >= off) ? s[t - off] : 0;
        __syncthreads();
        s[t] += v;
    }
    __syncthreads();
    boff[t] = s[t] - x;  // exclusive
}

__global__ void k_scan3(int* __restrict__ rowptr, const int* __restrict__ cnt,
                        const int* __restrict__ boff, int* __restrict__ cursor,
                        int N, int E) {
    int i = blockIdx.x * blockDim.x + threadIdx.x;
    if (i < N) {
        int excl = rowptr[i] - cnt[i] + boff[i >> 10];
        rowptr[i] = excl;
        cursor[i] = excl;
    }
    if (i == 0) rowptr[N] = E;
}

__global__ void k_fill(const int* __restrict__ row, const int* __restrict__ col,
                       const float* __restrict__ dinv, int* __restrict__ cursor,
                       int2* __restrict__ pairs, int E) {
    int e = blockIdx.x * blockDim.x + threadIdx.x;
    if (e >= E) return;
    int s = row[e], d = col[e];
    int slot = atomicAdd(&cursor[d], 1);
    float w = dinv[s] * dinv[d];
    pairs[slot] = make_int2(s, __float_as_int(w));
}

// ---- sparse aggregate: hout[i] = sum_in-edges hin[src]*w + hin[i]*dinv[i]^2
// one wave (64 lanes) per node; lane handles 2 features (float2, 8B/lane).
__global__ __launch_bounds__(256) void k_agg(const float* __restrict__ hin,
                                             const int2* __restrict__ pairs,
                                             const int* __restrict__ rowptr,
                                             const float* __restrict__ dinv,
                                             float* __restrict__ hout, int N) {
    int wid = threadIdx.x >> 6;
    int lane = threadIdx.x & 63;
    int node = blockIdx.x * 4 + wid;
    if (node >= N) return;
    const float2* h2 = (const float2*)hin;
    float di = dinv[node];
    float w0 = di * di;
    float2 self = h2[(size_t)node * 64 + lane];
    float2 acc;
    acc.x = self.x * w0;
    acc.y = self.y * w0;
    int r0 = rowptr[node], r1 = rowptr[node + 1];
    int j = r0;
    for (; j + 1 < r1; j += 2) {
        int2 p0 = pairs[j];
        int2 p1 = pairs[j + 1];
        float2 v0 = h2[(size_t)p0.x * 64 + lane];
        float2 v1 = h2[(size_t)p1.x * 64 + lane];
        float a0 = __int_as_float(p0.y), a1 = __int_as_float(p1.y);
        acc.x += v0.x * a0; acc.y += v0.y * a0;
        acc.x += v1.x * a1; acc.y += v1.y * a1;
    }
    if (j < r1) {
        int2 p = pairs[j];
        float2 v = h2[(size_t)p.x * 64 + lane];
        float a = __int_as_float(p.y);
        acc.x += v.x * a; acc.y += v.y * a;
    }
    ((float2*)hout)[(size_t)node * 64 + lane] = acc;
}

// ---- dense: out = relu(in @ W + b), in [N,128], W [128,128] ----------------
__global__ __launch_bounds__(256) void k_gemm(const float* __restrict__ in,
                                              const float* __restrict__ W,
                                              const float* __restrict__ bias,
                                              float* __restrict__ out, int N) {
    __shared__ float Wl[128 * 128];   // 64 KB
    __shared__ float Il[32 * 128];    // 16 KB
    int t = threadIdx.x;
    int nb = blockIdx.x * 32;
    const float4* W4 = (const float4*)W;
    float4* Wl4 = (float4*)Wl;
#pragma unroll
    for (int i = 0; i < 16; ++i) Wl4[t + i * 256] = W4[t + i * 256];
    int rows = N - nb; if (rows > 32) rows = 32;
    int lim4 = rows * 32;  // float4 count valid
    const float4* I4 = (const float4*)(in + (size_t)nb * 128);
    float4* Il4 = (float4*)Il;
#pragma unroll
    for (int i = 0; i < 4; ++i) {
        int id = t + i * 256;
        float4 v = make_float4(0.f, 0.f, 0.f, 0.f);
        if (id < lim4) v = I4[id];
        Il4[id] = v;
    }
    __syncthreads();
    int f0 = (t & 31) * 4;
    int n0 = (t >> 5) * 4;
    float acc[4][4];
#pragma unroll
    for (int i = 0; i < 4; ++i)
#pragma unroll
        for (int jj = 0; jj < 4; ++jj) acc[i][jj] = 0.f;

    for (int kk = 0; kk < 128; kk += 4) {
        float4 wr[4], hr[4];
#pragma unroll
        for (int d = 0; d < 4; ++d) wr[d] = *(const float4*)&Wl[(kk + d) * 128 + f0];
#pragma unroll
        for (int i = 0; i < 4; ++i) hr[i] = *(const float4*)&Il[(n0 + i) * 128 + kk];
#pragma unroll
        for (int i = 0; i < 4; ++i) {
            const float* hv = (const float*)&hr[i];
#pragma unroll
            for (int d = 0; d < 4; ++d) {
                const float* wv = (const float*)&wr[d];
                float h = hv[d];
                acc[i][0] += h * wv[0];
                acc[i][1] += h * wv[1];
                acc[i][2] += h * wv[2];
                acc[i][3] += h * wv[3];
            }
        }
    }
    float4 bb = *(const float4*)&bias[f0];
#pragma unroll
    for (int i = 0; i < 4; ++i) {
        int n = nb + n0 + i;
        if (n < N) {
            float4 r;
            r.x = fmaxf(acc[i][0] + bb.x, 0.f);
            r.y = fmaxf(acc[i][1] + bb.y, 0.f);
            r.z = fmaxf(acc[i][2] + bb.z, 0.f);
            r.w = fmaxf(acc[i][3] + bb.w, 0.f);
            *(float4*)&out[(size_t)n * 128 + f0] = r;
        }
    }
}

// ---- mean-pool per graph (batch sorted): run-length partial sums -----------
__global__ __launch_bounds__(128) void k_pool(const float* __restrict__ h,
                                              const int* __restrict__ batch,
                                              float* __restrict__ pooled,
                                              float* __restrict__ gcnt, int N) {
    int t = threadIdx.x;
    int base = blockIdx.x * 128;
    if (base >= N) return;
    int end = base + 128; if (end > N) end = N;
    int g = batch[base];
    float acc = 0.f;
    int run = 0;
    for (int n = base; n < end; ++n) {
        int bg = batch[n];
        if (bg != g) {
            atomicAdd(&pooled[g * 128 + t], acc);
            if (t == 0) atomicAdd(&gcnt[g], (float)run);
            acc = 0.f; run = 0; g = bg;
        }
        acc += h[(size_t)n * 128 + t];
        run++;
    }
    atomicAdd(&pooled[g * 128 + t], acc);
    if (t == 0) atomicAdd(&gcnt[g], (float)run);
}

// ---- FFN: out[g] = relu(pooled_mean @ Wf1 + bf1) @ Wf2 + bf2 ---------------
__global__ __launch_bounds__(128) void k_ffn(const float* __restrict__ pooled,
                                             const float* __restrict__ gcnt,
                                             const float* __restrict__ Wf1,
                                             const float* __restrict__ bf1,
                                             const float* __restrict__ Wf2,
                                             const float* __restrict__ bf2,
                                             float* __restrict__ out, int C) {
    __shared__ float pl[128];
    __shared__ float hid[128];
    int g = blockIdx.x;
    int t = threadIdx.x;
    float invc = 1.0f / fmaxf(gcnt[g], 1.0f);
    pl[t] = pooled[g * 128 + t] * invc;
    __syncthreads();
    float s = bf1[t];
    for (int k = 0; k < 128; ++k) s += pl[k] * Wf1[k * 128 + t];
    hid[t] = fmaxf(s, 0.f);
    __syncthreads();
    if (t < C) {
        float o = bf2[t];
        for (int f = 0; f < 128; ++f) o += hid[f] * Wf2[f * C + t];
        out[g * C + t] = o;
    }
}

extern "C" void kernel_launch(void* const* d_in, const int* in_sizes, int n_in,
                              void* d_out, int out_size, void* d_ws, size_t ws_size,
                              hipStream_t stream) {
    const float* x   = (const float*)d_in[0];
    const int*   ei  = (const int*)d_in[1];
    const int*   bat = (const int*)d_in[2];
    const float* W1  = (const float*)d_in[3];
    const float* b1  = (const float*)d_in[4];
    const float* W2  = (const float*)d_in[5];
    const float* b2  = (const float*)d_in[6];
    const float* W3  = (const float*)d_in[7];
    const float* b3  = (const float*)d_in[8];
    const float* Wf1 = (const float*)d_in[9];
    const float* bf1 = (const float*)d_in[10];
    const float* Wf2 = (const float*)d_in[11];
    const float* bf2 = (const float*)d_in[12];
    float* out = (float*)d_out;

    int N = in_sizes[2];
    int E = in_sizes[1] / 2;
    int C = in_sizes[12];           // bf2 size
    const int* row  = ei;
    const int* colv = ei + E;

    char* w = (char*)d_ws;
    float* bufA  = (float*)w; w += (size_t)N * 128 * 4;
    float* bufB  = (float*)w; w += (size_t)N * 128 * 4;
    int2*  pairs = (int2*)w;  w += (size_t)E * 8;
    int* rowptr  = (int*)w;   w += (size_t)(N + 1) * 4;
    int* cursor  = (int*)w;   w += (size_t)N * 4;
    int* cnt     = (int*)w;   w += (size_t)N * 4;
    float* dinv  = (float*)w; w += (size_t)N * 4;
    int* bsums   = (int*)w;   w += 1024 * 4;
    int* boff    = (int*)w;   w += 1024 * 4;
    float* pooled= (float*)w; w += 128 * 128 * 4;
    float* gcnt  = (float*)w; w += 128 * 4;

    int nbN = (N + 255) / 256;
    int nbE = (E + 255) / 256;
    int nsb = (N + 1023) / 1024;

    k_init <<<nbN, 256, 0, stream>>>(cnt, pooled, gcnt, N);
    k_count<<<nbE, 256, 0, stream>>>(colv, cnt, E);
    k_dinv <<<nbN, 256, 0, stream>>>(cnt, dinv, N);
    k_scan1<<<nsb, 1024, 0, stream>>>(cnt, rowptr, bsums, N);
    k_scan2<<<1, 1024, 0, stream>>>(bsums, boff, nsb);
    k_scan3<<<nbN, 256, 0, stream>>>(rowptr, cnt, boff, cursor, N, E);
    k_fill <<<nbE, 256, 0, stream>>>(row, colv, dinv, cursor, pairs, E);

    int nagg = (N + 3) / 4;
    int ngemm = (N + 31) / 32;
    // layer 1
    k_agg <<<nagg, 256, 0, stream>>>(x, pairs, rowptr, dinv, bufB, N);
    k_gemm<<<ngemm, 256, 0, stream>>>(bufB, W1, b1, bufA, N);
    // layer 2
    k_agg <<<nagg, 256, 0, stream>>>(bufA, pairs, rowptr, dinv, bufB, N);
    k_gemm<<<ngemm, 256, 0, stream>>>(bufB, W2, b2, bufA, N);
    // layer 3
    k_agg <<<nagg, 256, 0, stream>>>(bufA, pairs, rowptr, dinv, bufB, N);
    k_gemm<<<ngemm, 256, 0, stream>>>(bufB, W3, b3, bufA, N);

    k_pool<<<(N + 127) / 128, 128, 0, stream>>>(bufA, bat, pooled, gcnt, N);
    k_ffn <<<128, 128, 0, stream>>>(pooled, gcnt, Wf1, bf1, Wf2, bf2, out, C);
}